// Round 3
// baseline (522.093 us; speedup 1.0000x reference)
//
#include <hip/hip_runtime.h>
#include <hip/hip_bf16.h>

typedef unsigned int u32;
typedef unsigned long long u64;
typedef float f32x4 __attribute__((ext_vector_type(4)));
typedef short s16x8 __attribute__((ext_vector_type(8)));

#define LDA 136  // padded LDS row stride (bf16 elems) for k1

// workspace layout (bytes)
#define WQT_OFF 0ULL
#define WKT_OFF 32768ULL
#define WVT_OFF 65536ULL
#define OPWT_OFF 98304ULL
#define Q_OFF 114688ULL
#define K_OFF (Q_OFF + 8388608ULL)
#define VT_OFF (K_OFF + 8388608ULL)
#define GATE_OFF (VT_OFF + 8388608ULL)
#define MASK_OFF (GATE_OFF + 16777216ULL)
// total ws need = MASK_OFF + 8.4 MiB ~= 50.4 MiB

__device__ __forceinline__ u32 f2bf(float f) {  // RNE float->bf16 bits
  u32 u = __float_as_uint(f);
  return (u + 0x7fffu + ((u >> 16) & 1u)) >> 16;
}

__device__ __forceinline__ u32 pk2bf(float a, float b) {  // packed pair via v_cvt_pk_bf16_f32
  __hip_bfloat162 h = __float22bfloat162_rn(make_float2(a, b));
  u32 r;
  __builtin_memcpy(&r, &h, 4);
  return r;
}

__device__ __forceinline__ void gl_lds16(const void* g, void* l) {
  __builtin_amdgcn_global_load_lds((const __attribute__((address_space(1))) void*)g,
                                   (__attribute__((address_space(3))) void*)l, 16, 0, 0);
}

// ---- k0: transpose weights to bf16; fold a_w * (1/sqrt(128)) * log2(e) into Wk^T ----
__global__ void k0_wt(const float* Wq, const float* Wk, const float* Wv,
                      const float* aw, const float* opW, char* ws) {
  int nt = blockIdx.x, part = blockIdx.y;
  int kksh = (nt == 3) ? 6 : 7;
  int KK = 1 << kksh;
  const float* S = (nt == 0) ? Wq : (nt == 1) ? Wk : (nt == 2) ? Wv : opW;
  unsigned short* D = (unsigned short*)(ws + (nt == 0 ? WQT_OFF : nt == 1 ? WKT_OFF : nt == 2 ? WVT_OFF : OPWT_OFF));
  int base = part * 8 * KK;
  for (int i = threadIdx.x; i < 8 * KK; i += 256) {
    int d = part * 8 + (i >> kksh), k = i & (KK - 1);
    float v = S[k * 128 + d];
    if (nt == 1) v *= aw[d] * 0.12751743f;  // (1/sqrt(128)) * log2(e)
    D[base + i] = (unsigned short)f2bf(v);
  }
}

// ---- k1: Q = h@Wq (bf16 [e][d]), K = h@Wk_scaled ([e][d]), Vt = (h@Wv)^T ([d][e]),
// ----     gate = sigmoid(op_emb@opW + op_b) (fp32 [e][d])
// ----     nt==4: adj -> 1-bit mask, BALLOT-FREE (R2 post-mortem: ballot is convergent,
// ----            sched_barrier fenced every iter -> no cross-row pipelining, ~700cy/load).
// ----            adj is exactly {0.0f,1.0f}; bit = (bits>>29)&1. Lane i owns floats
// ----            [i*128,i*128+128) of a row = ONE 128-B line/lane (8x uint4, L1-clean),
// ----            pure per-lane pack, u32/lane store (256 B/row contiguous). Linear bit order.
__launch_bounds__(256, 2)
__global__ void k1_proj(const float* __restrict__ h, const float* __restrict__ op_emb,
                        const float* __restrict__ op_b, const float* __restrict__ adj,
                        char* __restrict__ ws) {
  int nt = blockIdx.x, et = blockIdx.y;
  if (nt == 4) {
    // block et handles 128 flattened (b,e) rows; wave handles 32 rows, lane owns 32 l's.
    const int w = threadIdx.x >> 6, lane = threadIdx.x & 63;
    u32* dst = (u32*)(ws + MASK_OFF) + (size_t)et * 8192 + lane;
    const char* base = (const char*)(adj + (size_t)et * 128 * 2048) + lane * 128;
#pragma unroll 2
    for (int r = w; r < 128; r += 4) {
      const uint4* rowp = (const uint4*)(base + (size_t)r * 8192);
      uint4 v[8];
#pragma unroll
      for (int j = 0; j < 8; j++) v[j] = rowp[j];
      u32 m = 0;
#pragma unroll
      for (int j = 0; j < 8; j++) {
        m |= ((v[j].x >> 29) & 1u) << (4 * j + 0);
        m |= ((v[j].y >> 29) & 1u) << (4 * j + 1);
        m |= ((v[j].z >> 29) & 1u) << (4 * j + 2);
        m |= ((v[j].w >> 29) & 1u) << (4 * j + 3);
      }
      dst[r * 64] = m;
    }
    return;
  }
  int kksh = (nt == 3) ? 6 : 7;
  int KK = 1 << kksh;
  __shared__ unsigned short bufA[128 * LDA];
  __shared__ unsigned short bufB[128 * LDA];
  unsigned short* wbuf = (nt == 2) ? bufB : bufA;
  unsigned short* xbuf = (nt == 2) ? bufA : bufB;
  const unsigned short* Wt = (const unsigned short*)(ws + (nt == 0 ? WQT_OFF : nt == 1 ? WKT_OFF : nt == 2 ? WVT_OFF : OPWT_OFF));
  {
    const uint4* Ws = (const uint4*)Wt;
    int cnt = 128 * KK / 8;
    for (int i = threadIdx.x; i < cnt; i += 256) {
      uint4 v = Ws[i];
      int r = (8 * i) >> kksh, c = (8 * i) & (KK - 1);
      *(uint4*)&wbuf[r * LDA + c] = v;
    }
  }
  {
    const float* X = (nt == 3) ? (op_emb + (size_t)et * 128 * 64) : (h + (size_t)et * 128 * 128);
    int cnt = 128 * KK / 4;
    for (int i = threadIdx.x; i < cnt; i += 256) {
      float4 v = *(const float4*)(X + 4 * i);
      int r = (4 * i) >> kksh, c = (4 * i) & (KK - 1);
      *(uint2*)&xbuf[r * LDA + c] = make_uint2(pk2bf(v.x, v.y), pk2bf(v.z, v.w));
    }
  }
  __syncthreads();
  int tid = threadIdx.x, w = tid >> 6, lane = tid & 63, l15 = lane & 15, q = lane >> 4;
  int wa = w >> 1, wb = w & 1;
  f32x4 acc[4][4];
#pragma unroll
  for (int a = 0; a < 4; a++)
#pragma unroll
    for (int bq = 0; bq < 4; bq++) acc[a][bq] = f32x4{0.f, 0.f, 0.f, 0.f};
  for (int ks = 0; ks < KK / 32; ks++) {
    s16x8 af[4], bf_[4];
#pragma unroll
    for (int mt = 0; mt < 4; mt++)
      af[mt] = *(const s16x8*)&bufA[(wa * 64 + mt * 16 + l15) * LDA + ks * 32 + q * 8];
#pragma unroll
    for (int n2 = 0; n2 < 4; n2++)
      bf_[n2] = *(const s16x8*)&bufB[(wb * 64 + n2 * 16 + l15) * LDA + ks * 32 + q * 8];
#pragma unroll
    for (int mt = 0; mt < 4; mt++)
#pragma unroll
      for (int n2 = 0; n2 < 4; n2++)
        acc[mt][n2] = __builtin_amdgcn_mfma_f32_16x16x32_bf16(af[mt], bf_[n2], acc[mt][n2], 0, 0, 0);
  }
  if (nt <= 1) {
    unsigned short* Dst = (unsigned short*)(ws + (nt == 0 ? Q_OFF : K_OFF));
#pragma unroll
    for (int mt = 0; mt < 4; mt++)
#pragma unroll
      for (int n2 = 0; n2 < 4; n2++) {
        int d0 = wa * 64 + mt * 16 + q * 4;
        int eg = et * 128 + wb * 64 + n2 * 16 + l15;
        f32x4 a = acc[mt][n2];
        *(uint2*)(Dst + (size_t)eg * 128 + d0) = make_uint2(pk2bf(a[0], a[1]), pk2bf(a[2], a[3]));
      }
  } else if (nt == 2) {
    unsigned short* Dst = (unsigned short*)(ws + VT_OFF);
    int b = et >> 4;
    int ein0 = (et & 15) * 128;
#pragma unroll
    for (int mt = 0; mt < 4; mt++)
#pragma unroll
      for (int n2 = 0; n2 < 4; n2++) {
        int e0b = ein0 + wa * 64 + mt * 16 + q * 4;
        int d = wb * 64 + n2 * 16 + l15;
        f32x4 a = acc[mt][n2];
        *(uint2*)(Dst + (size_t)b * 128 * 2048 + (size_t)d * 2048 + e0b) =
            make_uint2(pk2bf(a[0], a[1]), pk2bf(a[2], a[3]));
      }
  } else {
    float* Dst = (float*)(ws + GATE_OFF);
#pragma unroll
    for (int mt = 0; mt < 4; mt++)
#pragma unroll
      for (int n2 = 0; n2 < 4; n2++) {
        int d0 = wa * 64 + mt * 16 + q * 4;
        int eg = et * 128 + wb * 64 + n2 * 16 + l15;
        f32x4 a = acc[mt][n2];
        float4 g4;
        g4.x = 1.f / (1.f + __builtin_amdgcn_exp2f(-(a[0] + op_b[d0 + 0]) * 1.4426950f));
        g4.y = 1.f / (1.f + __builtin_amdgcn_exp2f(-(a[1] + op_b[d0 + 1]) * 1.4426950f));
        g4.z = 1.f / (1.f + __builtin_amdgcn_exp2f(-(a[2] + op_b[d0 + 2]) * 1.4426950f));
        g4.w = 1.f / (1.f + __builtin_amdgcn_exp2f(-(a[3] + op_b[d0 + 3]) * 1.4426950f));
        *(float4*)(Dst + (size_t)eg * 128 + d0) = g4;
      }
  }
}

// ---- k2: fused attention + gate + LayerNorm. 256 threads, 64 e-rows, 512 blocks.
// LDS = exactly 80 KB -> 2 blocks/CU; sibling block hides vmcnt(0) barrier drains.
// adj arrives as a 1-bit mask (16 B/thread/iter, L2-resident), LINEAR bit order:
// word w of a row covers l in [32w,32w+32), bit = l&31. exp2(bit ? x : 0) == lrelu*adj.
__launch_bounds__(256, 2)
__global__ void k2_attn(const float* __restrict__ ln_g, const float* __restrict__ ln_b,
                        char* __restrict__ ws, float* __restrict__ out) {
  __shared__ char smem[81920];
  char* Klds = smem;           // K tile [l=128][k=128] bf16, rows 256 B
  char* Vlds = smem + 32768;   // Vt tile [d=128][l=128] bf16, rows 256 B
  char* PL = smem + 65536;     // P [e=64][l=128] bf16, rows 256 B (shared across waves)

  const int bid = blockIdx.x;
  const int xcd = bid & 7, slot = bid >> 3;
  const int b = xcd * 2 + (slot >> 5);  // 2 batches per XCD: K/Vt stay L2-resident
  const int e0 = (slot & 31) << 6;

  const unsigned short* Qg = (const unsigned short*)(ws + Q_OFF) + ((size_t)b * 2048 + e0) * 128;
  const unsigned short* Kg = (const unsigned short*)(ws + K_OFF) + (size_t)b * 2048 * 128;
  const unsigned short* Vtg = (const unsigned short*)(ws + VT_OFF) + (size_t)b * 128 * 2048;
  const float* gateg = (const float*)(ws + GATE_OFF) + ((size_t)b * 2048 + e0) * 128;
  const uint4* maskg = (const uint4*)(ws + MASK_OFF) + ((size_t)b * 2048 + e0) * 16;

  const int tid = threadIdx.x;
  const int w = tid >> 6, lane = tid & 63, l15 = lane & 15, q = lane >> 4;
  const int wh = w >> 1, we = w & 1;  // wh: l-half (GEMM1) / d-half (GEMM2); we: e-half

  // persistent Q B-frags: B[k=proj][n=e]
  s16x8 qf[2][4];
#pragma unroll
  for (int et = 0; et < 2; et++) {
    const int e = we * 32 + et * 16 + l15;
#pragma unroll
    for (int ks = 0; ks < 4; ks++)
      qf[et][ks] = *(const s16x8*)(Qg + (size_t)e * 128 + ks * 32 + q * 8);
  }

  // O accumulators: C[m=e (2 et)][n=d (4 dt, this wave's d-half)] - 32 VGPRs
  f32x4 oacc[2][4];
#pragma unroll
  for (int et = 0; et < 2; et++)
#pragma unroll
    for (int dt = 0; dt < 4; dt++) oacc[et][dt] = f32x4{0.f, 0.f, 0.f, 0.f};
  float dp0 = 0.0f, dp1 = 0.0f;  // denominator partials (this thread's P cells)
  uint4 mA[2], mB[2];            // adj bitmask for iter it / it+1 (4 words per e-row chunk)

  // prolog: DMA K(0), Vt(0); load mask(0)
#pragma unroll
  for (int j = 0; j < 8; j++) {
    int S = (j * 4 + w) * 64 + lane;
    int r = S >> 4, c = (S & 15) ^ (r & 15);
    gl_lds16(Kg + (size_t)r * 128 + (c << 3), Klds + (j * 4 + w) * 1024);
    gl_lds16(Vtg + (size_t)r * 2048 + (c << 3), Vlds + (j * 4 + w) * 1024);
  }
#pragma unroll
  for (int et = 0; et < 2; et++)
    mB[et] = maskg[(size_t)(we * 32 + et * 16 + l15) * 16];

#pragma unroll 1
  for (int it = 0; it < 16; it++) {
    __syncthreads();  // [A] K(it)/Vt(it) DMA drained; PL(it-1) consumed
    mA[0] = mB[0];
    mA[1] = mB[1];
    if (it < 15) {  // mask(it+1) into regs; in flight under GEMM1
#pragma unroll
      for (int et = 0; et < 2; et++)
        mB[et] = maskg[(size_t)(we * 32 + et * 16 + l15) * 16 + it + 1];
    }

    // GEMM1: St[l][e] = K_tile @ Q^T (scale/log2e pre-folded into K)
    f32x4 sacc[4][2];
#pragma unroll
    for (int lt = 0; lt < 4; lt++)
#pragma unroll
      for (int et = 0; et < 2; et++) sacc[lt][et] = f32x4{0.f, 0.f, 0.f, 0.f};
#pragma unroll
    for (int ks = 0; ks < 4; ks++) {
      s16x8 kf[4];
#pragma unroll
      for (int lt = 0; lt < 4; lt++) {
        int l = wh * 64 + lt * 16 + l15;
        kf[lt] = *(const s16x8*)(Klds + l * 256 + (((ks * 4 + q) ^ l15) << 4));
      }
#pragma unroll
      for (int lt = 0; lt < 4; lt++)
#pragma unroll
        for (int et = 0; et < 2; et++)
          sacc[lt][et] = __builtin_amdgcn_mfma_f32_16x16x32_bf16(kf[lt], qf[et][ks], sacc[lt][et], 0, 0, 0);
    }

    // P = exp2(bit ? lrelu(s) : 0); accumulate denom; pack bf16 -> PL (swizzled).
    // Element j at l' = wh*64+lt*16+q*4+j: word = wh*2+(lt>>1), bit = (lt&1)*16+q*4+j.
#pragma unroll
    for (int et = 0; et < 2; et++) {
      const int e = we * 32 + et * 16 + l15;
      float dsum = 0.0f;
#pragma unroll
      for (int lt = 0; lt < 4; lt++) {
        const u32 word = (wh == 0) ? ((lt < 2) ? mA[et].x : mA[et].y)
                                   : ((lt < 2) ? mA[et].z : mA[et].w);
        const u32 nib = word >> ((lt & 1) * 16 + q * 4);
        f32x4 s = sacc[lt][et];
        float x0 = (nib & 1u) ? fmaxf(s[0], 0.2f * s[0]) : 0.0f;
        float x1 = (nib & 2u) ? fmaxf(s[1], 0.2f * s[1]) : 0.0f;
        float x2 = (nib & 4u) ? fmaxf(s[2], 0.2f * s[2]) : 0.0f;
        float x3 = (nib & 8u) ? fmaxf(s[3], 0.2f * s[3]) : 0.0f;
        float p0 = __builtin_amdgcn_exp2f(x0);
        float p1 = __builtin_amdgcn_exp2f(x1);
        float p2 = __builtin_amdgcn_exp2f(x2);
        float p3 = __builtin_amdgcn_exp2f(x3);
        dsum += (p0 + p1) + (p2 + p3);
        // l = wh*64 + lt*16 + q*4 -> chunk = l>>3, half = q&1
        int chunk = wh * 8 + lt * 2 + (q >> 1);
        *(uint2*)(PL + e * 256 + ((chunk ^ l15) << 4) + (q & 1) * 8) =
            make_uint2(pk2bf(p0, p1), pk2bf(p2, p3));
      }
      if (et == 0) dp0 += dsum; else dp1 += dsum;
    }
    __syncthreads();  // [B] PL ready; Klds free (all GEMM1 reads done)

    if (it < 15) {  // DMA K(it+1); in flight until [A](it+1)
      const unsigned short* kb = Kg + (size_t)(it + 1) * 16384;
#pragma unroll
      for (int j = 0; j < 8; j++) {
        int S = (j * 4 + w) * 64 + lane;
        int r = S >> 4, c = (S & 15) ^ (r & 15);
        gl_lds16(kb + (size_t)r * 128 + (c << 3), Klds + (j * 4 + w) * 1024);
      }
    }

    // GEMM2: O[e][d-half] += P[e][l] * Vt[d][l], k = all 128 l
#pragma unroll
    for (int ks = 0; ks < 4; ks++) {
      s16x8 af[2], vf[4];
#pragma unroll
      for (int et = 0; et < 2; et++) {
        const int e = we * 32 + et * 16 + l15;
        af[et] = *(const s16x8*)(PL + e * 256 + (((ks * 4 + q) ^ l15) << 4));
      }
#pragma unroll
      for (int dt = 0; dt < 4; dt++) {
        int d = wh * 64 + dt * 16 + l15;
        vf[dt] = *(const s16x8*)(Vlds + d * 256 + (((ks * 4 + q) ^ l15) << 4));
      }
#pragma unroll
      for (int et = 0; et < 2; et++)
#pragma unroll
        for (int dt = 0; dt < 4; dt++)
          oacc[et][dt] = __builtin_amdgcn_mfma_f32_16x16x32_bf16(af[et], vf[dt], oacc[et][dt], 0, 0, 0);
    }
    __syncthreads();  // [C] Vlds free (all GEMM2 reads done); PL free at next [A]

    if (it < 15) {  // DMA Vt(it+1); drains at [A](it+1) under sibling cover
      const unsigned short* vb = Vtg + (size_t)(it + 1) * 128;
#pragma unroll
      for (int j = 0; j < 8; j++) {
        int S = (j * 4 + w) * 64 + lane;
        int r = S >> 4, c = (S & 15) ^ (r & 15);
        gl_lds16(vb + (size_t)r * 2048 + (c << 3), Vlds + (j * 4 + w) * 1024);
      }
    }
  }

  // ---- epilogue ----
  // sden overlays the now-dead PL region (LDS total stays 81920 -> 2 blocks/CU)
  float* sden = (float*)(smem + 65536);
  if (tid < 64) sden[tid] = 0.0f;
  __syncthreads();  // sden zeroed (also: all PL reads done before overlay write)
  atomicAdd(&sden[we * 32 + l15], dp0);        // 8 contributors per e (2 wh x 4 q)
  atomicAdd(&sden[we * 32 + 16 + l15], dp1);

  // O2 [e=64][d=128] fp32 stride 132 overlays dead K/V tiles (33.8 KB)
  float* O2 = (float*)smem;
#pragma unroll
  for (int et = 0; et < 2; et++)
#pragma unroll
    for (int dt = 0; dt < 4; dt++) {
      const int eb = we * 32 + et * 16 + q * 4;
      const int d = wh * 64 + dt * 16 + l15;
      f32x4 v = oacc[et][dt];
#pragma unroll
      for (int r = 0; r < 4; r++) O2[(eb + r) * 132 + d] = v[r];
    }
  __syncthreads();  // O2 + sden visible

  // hp = gate * (O/den); LayerNorm; store. 4 threads per token, 32 features each.
  {
    const int e = tid >> 2, j = tid & 3;
    const float inv = 1.0f / sden[e];
    const float* row = O2 + e * 132 + j * 32;
    const float* gr = gateg + (size_t)e * 128 + j * 32;
    float4 x[8];
    float s1 = 0.f, s2 = 0.f;
#pragma unroll
    for (int i = 0; i < 8; i++) {
      float4 v = *(const float4*)(row + i * 4);
      float4 g = *(const float4*)(gr + i * 4);
      float4 hp;
      hp.x = v.x * inv * g.x; hp.y = v.y * inv * g.y;
      hp.z = v.z * inv * g.z; hp.w = v.w * inv * g.w;
      x[i] = hp;
      s1 += (hp.x + hp.y) + (hp.z + hp.w);
      s2 += (hp.x * hp.x + hp.y * hp.y) + (hp.z * hp.z + hp.w * hp.w);
    }
    s1 += __shfl_xor(s1, 1); s2 += __shfl_xor(s2, 1);
    s1 += __shfl_xor(s1, 2); s2 += __shfl_xor(s2, 2);
    const float mu = s1 * 0.0078125f;
    const float var = s2 * 0.0078125f - mu * mu;
    const float rs = rsqrtf(var + 1e-5f);
    float* orow = out + ((size_t)b * 2048 + e0 + e) * 128 + j * 32;
    const float* gg = ln_g + j * 32;
    const float* bb = ln_b + j * 32;
#pragma unroll
    for (int i = 0; i < 8; i++) {
      float4 gv = *(const float4*)(gg + i * 4);
      float4 bv = *(const float4*)(bb + i * 4);
      float4 o;
      o.x = (x[i].x - mu) * rs * gv.x + bv.x;
      o.y = (x[i].y - mu) * rs * gv.y + bv.y;
      o.z = (x[i].z - mu) * rs * gv.z + bv.z;
      o.w = (x[i].w - mu) * rs * gv.w + bv.w;
      *(float4*)(orow + i * 4) = o;
    }
  }
}

extern "C" void kernel_launch(void* const* d_in, const int* in_sizes, int n_in,
                              void* d_out, int out_size, void* d_ws, size_t ws_size,
                              hipStream_t stream) {
  const float* h = (const float*)d_in[0];
  const float* adj = (const float*)d_in[1];
  const float* op_emb = (const float*)d_in[2];
  const float* Wk = (const float*)d_in[3];
  const float* Wq = (const float*)d_in[4];
  const float* Wv = (const float*)d_in[5];
  const float* a_w = (const float*)d_in[6];
  const float* op_W = (const float*)d_in[7];
  const float* op_b = (const float*)d_in[8];
  const float* ln_g = (const float*)d_in[9];
  const float* ln_b = (const float*)d_in[10];
  char* ws = (char*)d_ws;
  float* out = (float*)d_out;

  k0_wt<<<dim3(4, 16), 256, 0, stream>>>(Wq, Wk, Wv, a_w, op_W, ws);
  k1_proj<<<dim3(5, 256), 256, 0, stream>>>(h, op_emb, op_b, adj, ws);
  k2_attn<<<512, 256, 0, stream>>>(ln_g, ln_b, ws, out);
}

// Round 4
// 449.088 us; speedup vs baseline: 1.1626x; 1.1626x over previous
//
#include <hip/hip_runtime.h>
#include <hip/hip_bf16.h>

typedef unsigned int u32;
typedef unsigned long long u64;
typedef float f32x4 __attribute__((ext_vector_type(4)));
typedef short s16x8 __attribute__((ext_vector_type(8)));

#define LDA 136  // padded LDS row stride (bf16 elems) for k1

// workspace layout (bytes)
#define WQT_OFF 0ULL
#define WKT_OFF 32768ULL
#define WVT_OFF 65536ULL
#define OPWT_OFF 98304ULL
#define Q_OFF 114688ULL
#define K_OFF (Q_OFF + 8388608ULL)
#define VT_OFF (K_OFF + 8388608ULL)
#define GATE_OFF (VT_OFF + 8388608ULL)
// total ws need = GATE_OFF + 16 MiB ~= 42 MiB

__device__ __forceinline__ u32 f2bf(float f) {  // RNE float->bf16 bits
  u32 u = __float_as_uint(f);
  return (u + 0x7fffu + ((u >> 16) & 1u)) >> 16;
}

__device__ __forceinline__ u32 pk2bf(float a, float b) {  // packed pair via v_cvt_pk_bf16_f32
  __hip_bfloat162 h = __float22bfloat162_rn(make_float2(a, b));
  u32 r;
  __builtin_memcpy(&r, &h, 4);
  return r;
}

__device__ __forceinline__ void gl_lds16(const void* g, void* l) {
  __builtin_amdgcn_global_load_lds((const __attribute__((address_space(1))) void*)g,
                                   (__attribute__((address_space(3))) void*)l, 16, 0, 0);
}

// ---- k0: transpose weights to bf16; fold a_w * (1/sqrt(128)) * log2(e) into Wk^T ----
__global__ void k0_wt(const float* Wq, const float* Wk, const float* Wv,
                      const float* aw, const float* opW, char* ws) {
  int nt = blockIdx.x, part = blockIdx.y;
  int kksh = (nt == 3) ? 6 : 7;
  int KK = 1 << kksh;
  const float* S = (nt == 0) ? Wq : (nt == 1) ? Wk : (nt == 2) ? Wv : opW;
  unsigned short* D = (unsigned short*)(ws + (nt == 0 ? WQT_OFF : nt == 1 ? WKT_OFF : nt == 2 ? WVT_OFF : OPWT_OFF));
  int base = part * 8 * KK;
  for (int i = threadIdx.x; i < 8 * KK; i += 256) {
    int d = part * 8 + (i >> kksh), k = i & (KK - 1);
    float v = S[k * 128 + d];
    if (nt == 1) v *= aw[d] * 0.12751743f;  // (1/sqrt(128)) * log2(e)
    D[base + i] = (unsigned short)f2bf(v);
  }
}

// ---- k1: Q = h@Wq (bf16 [e][d]), K = h@Wk_scaled ([e][d]), Vt = (h@Wv)^T ([d][e]),
// ----     gate = sigmoid(op_emb@opW + op_b) (fp32 [e][d]).
// ----     (R3 post-mortem: mask pass removed — it ran under the fill-writeback shadow
// ----      at a 1.3 TB/s leftover share regardless of loop structure. adj is consumed
// ----      inline by k2, which runs last when HBM BW is available.)
__launch_bounds__(256, 2)
__global__ void k1_proj(const float* __restrict__ h, const float* __restrict__ op_emb,
                        const float* __restrict__ op_b, char* __restrict__ ws) {
  int nt = blockIdx.x, et = blockIdx.y;
  int kksh = (nt == 3) ? 6 : 7;
  int KK = 1 << kksh;
  __shared__ unsigned short bufA[128 * LDA];
  __shared__ unsigned short bufB[128 * LDA];
  unsigned short* wbuf = (nt == 2) ? bufB : bufA;
  unsigned short* xbuf = (nt == 2) ? bufA : bufB;
  const unsigned short* Wt = (const unsigned short*)(ws + (nt == 0 ? WQT_OFF : nt == 1 ? WKT_OFF : nt == 2 ? WVT_OFF : OPWT_OFF));
  {
    const uint4* Ws = (const uint4*)Wt;
    int cnt = 128 * KK / 8;
    for (int i = threadIdx.x; i < cnt; i += 256) {
      uint4 v = Ws[i];
      int r = (8 * i) >> kksh, c = (8 * i) & (KK - 1);
      *(uint4*)&wbuf[r * LDA + c] = v;
    }
  }
  {
    const float* X = (nt == 3) ? (op_emb + (size_t)et * 128 * 64) : (h + (size_t)et * 128 * 128);
    int cnt = 128 * KK / 4;
    for (int i = threadIdx.x; i < cnt; i += 256) {
      float4 v = *(const float4*)(X + 4 * i);
      int r = (4 * i) >> kksh, c = (4 * i) & (KK - 1);
      *(uint2*)&xbuf[r * LDA + c] = make_uint2(pk2bf(v.x, v.y), pk2bf(v.z, v.w));
    }
  }
  __syncthreads();
  int tid = threadIdx.x, w = tid >> 6, lane = tid & 63, l15 = lane & 15, q = lane >> 4;
  int wa = w >> 1, wb = w & 1;
  f32x4 acc[4][4];
#pragma unroll
  for (int a = 0; a < 4; a++)
#pragma unroll
    for (int bq = 0; bq < 4; bq++) acc[a][bq] = f32x4{0.f, 0.f, 0.f, 0.f};
  for (int ks = 0; ks < KK / 32; ks++) {
    s16x8 af[4], bf_[4];
#pragma unroll
    for (int mt = 0; mt < 4; mt++)
      af[mt] = *(const s16x8*)&bufA[(wa * 64 + mt * 16 + l15) * LDA + ks * 32 + q * 8];
#pragma unroll
    for (int n2 = 0; n2 < 4; n2++)
      bf_[n2] = *(const s16x8*)&bufB[(wb * 64 + n2 * 16 + l15) * LDA + ks * 32 + q * 8];
#pragma unroll
    for (int mt = 0; mt < 4; mt++)
#pragma unroll
      for (int n2 = 0; n2 < 4; n2++)
        acc[mt][n2] = __builtin_amdgcn_mfma_f32_16x16x32_bf16(af[mt], bf_[n2], acc[mt][n2], 0, 0, 0);
  }
  if (nt <= 1) {
    unsigned short* Dst = (unsigned short*)(ws + (nt == 0 ? Q_OFF : K_OFF));
#pragma unroll
    for (int mt = 0; mt < 4; mt++)
#pragma unroll
      for (int n2 = 0; n2 < 4; n2++) {
        int d0 = wa * 64 + mt * 16 + q * 4;
        int eg = et * 128 + wb * 64 + n2 * 16 + l15;
        f32x4 a = acc[mt][n2];
        *(uint2*)(Dst + (size_t)eg * 128 + d0) = make_uint2(pk2bf(a[0], a[1]), pk2bf(a[2], a[3]));
      }
  } else if (nt == 2) {
    unsigned short* Dst = (unsigned short*)(ws + VT_OFF);
    int b = et >> 4;
    int ein0 = (et & 15) * 128;
#pragma unroll
    for (int mt = 0; mt < 4; mt++)
#pragma unroll
      for (int n2 = 0; n2 < 4; n2++) {
        int e0b = ein0 + wa * 64 + mt * 16 + q * 4;
        int d = wb * 64 + n2 * 16 + l15;
        f32x4 a = acc[mt][n2];
        *(uint2*)(Dst + (size_t)b * 128 * 2048 + (size_t)d * 2048 + e0b) =
            make_uint2(pk2bf(a[0], a[1]), pk2bf(a[2], a[3]));
      }
  } else {
    float* Dst = (float*)(ws + GATE_OFF);
#pragma unroll
    for (int mt = 0; mt < 4; mt++)
#pragma unroll
      for (int n2 = 0; n2 < 4; n2++) {
        int d0 = wa * 64 + mt * 16 + q * 4;
        int eg = et * 128 + wb * 64 + n2 * 16 + l15;
        f32x4 a = acc[mt][n2];
        float4 g4;
        g4.x = 1.f / (1.f + __builtin_amdgcn_exp2f(-(a[0] + op_b[d0 + 0]) * 1.4426950f));
        g4.y = 1.f / (1.f + __builtin_amdgcn_exp2f(-(a[1] + op_b[d0 + 1]) * 1.4426950f));
        g4.z = 1.f / (1.f + __builtin_amdgcn_exp2f(-(a[2] + op_b[d0 + 2]) * 1.4426950f));
        g4.w = 1.f / (1.f + __builtin_amdgcn_exp2f(-(a[3] + op_b[d0 + 3]) * 1.4426950f));
        *(float4*)(Dst + (size_t)eg * 128 + d0) = g4;
      }
  }
}

// Raw barriers with COUNTED waits (T3/T4): never drain vmcnt(0) except where the
// newest outstanding op is the one we need. Per-wave vmcnt ledger (steady state):
//   post-[B](it-1): K(it) DMA x8, then adj(it) x8  (order pinned by sched_barrier)
//   post-[C](it-1): V(it) DMA x8
//   [A](it):  wait vmcnt(8)  -> K(it)+adj(it) done, V(it) still in flight
//   [B](it):  wait vmcnt(0)  -> V(it) done (only V outstanding; full GEMM1+softmax cover)
//   [C](it):  lgkmcnt(0) only -> K(it+1)/adj(it+1) stay in flight across it
#define BAR_A do { asm volatile("s_waitcnt vmcnt(8) lgkmcnt(0)\n\ts_barrier" ::: "memory"); \
                   __builtin_amdgcn_sched_barrier(0); } while (0)
#define BAR_B do { asm volatile("s_waitcnt vmcnt(0) lgkmcnt(0)\n\ts_barrier" ::: "memory"); \
                   __builtin_amdgcn_sched_barrier(0); } while (0)
#define BAR_C do { asm volatile("s_waitcnt lgkmcnt(0)\n\ts_barrier" ::: "memory"); \
                   __builtin_amdgcn_sched_barrier(0); } while (0)

// ---- k2: fused attention + gate + LayerNorm. 256 threads, 64 e-rows, 512 blocks.
// LDS = exactly 80 KB -> 2 blocks/CU. adj consumed inline (fp32, multiply-form mask),
// prefetched 1 iteration ahead into 32 VGPRs at [B] (cover = GEMM2 + [A] + GEMM1).
__launch_bounds__(256, 2)
__global__ void k2_attn(const float* __restrict__ adj, const float* __restrict__ ln_g,
                        const float* __restrict__ ln_b, char* __restrict__ ws,
                        float* __restrict__ out) {
  __shared__ char smem[81920];
  char* Klds = smem;           // K tile [l=128][k=128] bf16, rows 256 B
  char* Vlds = smem + 32768;   // Vt tile [d=128][l=128] bf16, rows 256 B
  char* PL = smem + 65536;     // P [e=64][l=128] bf16, rows 256 B (shared across waves)

  const int bid = blockIdx.x;
  const int xcd = bid & 7, slot = bid >> 3;
  const int b = xcd * 2 + (slot >> 5);  // 2 batches per XCD: K/Vt stay L2-resident
  const int e0 = (slot & 31) << 6;

  const unsigned short* Qg = (const unsigned short*)(ws + Q_OFF) + ((size_t)b * 2048 + e0) * 128;
  const unsigned short* Kg = (const unsigned short*)(ws + K_OFF) + (size_t)b * 2048 * 128;
  const unsigned short* Vtg = (const unsigned short*)(ws + VT_OFF) + (size_t)b * 128 * 2048;
  const float* gateg = (const float*)(ws + GATE_OFF) + ((size_t)b * 2048 + e0) * 128;
  const float* adjg = adj + (size_t)b * 2048 * 2048 + (size_t)e0 * 2048;

  const int tid = threadIdx.x;
  const int w = tid >> 6, lane = tid & 63, l15 = lane & 15, q = lane >> 4;
  const int wh = w >> 1, we = w & 1;  // wh: l-half (GEMM1) / d-half (GEMM2); we: e-half

  // persistent Q B-frags: B[k=proj][n=e]
  s16x8 qf[2][4];
#pragma unroll
  for (int et = 0; et < 2; et++) {
    const int e = we * 32 + et * 16 + l15;
#pragma unroll
    for (int ks = 0; ks < 4; ks++)
      qf[et][ks] = *(const s16x8*)(Qg + (size_t)e * 128 + ks * 32 + q * 8);
  }
  __builtin_amdgcn_sched_barrier(0);

  // O accumulators + denominator partials
  f32x4 oacc[2][4];
#pragma unroll
  for (int et = 0; et < 2; et++)
#pragma unroll
    for (int dt = 0; dt < 4; dt++) oacc[et][dt] = f32x4{0.f, 0.f, 0.f, 0.f};
  float dp0 = 0.0f, dp1 = 0.0f;
  float4 av[2][4];  // adj(it) fp32, single-buffered: written at [B](it-1), read in softmax(it)

  // prolog ledger: K(0) x8, V(0) x8, adj(0) x8 (orders pinned)
#pragma unroll
  for (int j = 0; j < 8; j++) {
    int S = (j * 4 + w) * 64 + lane;
    int r = S >> 4, c = (S & 15) ^ (r & 15);
    gl_lds16(Kg + (size_t)r * 128 + (c << 3), Klds + (j * 4 + w) * 1024);
  }
  __builtin_amdgcn_sched_barrier(0);
#pragma unroll
  for (int j = 0; j < 8; j++) {
    int S = (j * 4 + w) * 64 + lane;
    int r = S >> 4, c = (S & 15) ^ (r & 15);
    gl_lds16(Vtg + (size_t)r * 2048 + (c << 3), Vlds + (j * 4 + w) * 1024);
  }
  __builtin_amdgcn_sched_barrier(0);
#pragma unroll
  for (int et = 0; et < 2; et++) {
    const int e = we * 32 + et * 16 + l15;
#pragma unroll
    for (int lt = 0; lt < 4; lt++)
      av[et][lt] = *(const float4*)(adjg + (size_t)e * 2048 + wh * 64 + lt * 16 + q * 4);
  }
  __builtin_amdgcn_sched_barrier(0);

#pragma unroll 1
  for (int it = 0; it < 16; it++) {
    BAR_A;  // K(it) resident (+adj(it) arrived); V(it) still in flight

    // GEMM1: St[l][e] = K_tile @ Q^T (scale/log2e pre-folded into K)
    f32x4 sacc[4][2];
#pragma unroll
    for (int lt = 0; lt < 4; lt++)
#pragma unroll
      for (int et = 0; et < 2; et++) sacc[lt][et] = f32x4{0.f, 0.f, 0.f, 0.f};
#pragma unroll
    for (int ks = 0; ks < 4; ks++) {
      s16x8 kf[4];
#pragma unroll
      for (int lt = 0; lt < 4; lt++) {
        int l = wh * 64 + lt * 16 + l15;
        kf[lt] = *(const s16x8*)(Klds + l * 256 + (((ks * 4 + q) ^ l15) << 4));
      }
#pragma unroll
      for (int lt = 0; lt < 4; lt++)
#pragma unroll
        for (int et = 0; et < 2; et++)
          sacc[lt][et] = __builtin_amdgcn_mfma_f32_16x16x32_bf16(kf[lt], qf[et][ks], sacc[lt][et], 0, 0, 0);
    }

    // P = exp2(lrelu(s)*adj) (adj=0 -> 1); accumulate denom; pack bf16 -> PL (swizzled)
#pragma unroll
    for (int et = 0; et < 2; et++) {
      const int e = we * 32 + et * 16 + l15;
      float dsum = 0.0f;
#pragma unroll
      for (int lt = 0; lt < 4; lt++) {
        float4 aj = av[et][lt];
        f32x4 s = sacc[lt][et];
        float p0 = __builtin_amdgcn_exp2f(fmaxf(s[0], 0.2f * s[0]) * aj.x);
        float p1 = __builtin_amdgcn_exp2f(fmaxf(s[1], 0.2f * s[1]) * aj.y);
        float p2 = __builtin_amdgcn_exp2f(fmaxf(s[2], 0.2f * s[2]) * aj.z);
        float p3 = __builtin_amdgcn_exp2f(fmaxf(s[3], 0.2f * s[3]) * aj.w);
        dsum += (p0 + p1) + (p2 + p3);
        int chunk = wh * 8 + lt * 2 + (q >> 1);
        *(uint2*)(PL + e * 256 + ((chunk ^ l15) << 4) + (q & 1) * 8) =
            make_uint2(pk2bf(p0, p1), pk2bf(p2, p3));
      }
      if (et == 0) dp0 += dsum; else dp1 += dsum;
    }

    BAR_B;  // V(it) done for ALL waves; PL ready; Klds free

    if (it < 15) {  // issue K(it+1) DMA then adj(it+1) loads (ORDER MATTERS for [A]'s vmcnt(8))
      const unsigned short* kb = Kg + (size_t)(it + 1) * 16384;
#pragma unroll
      for (int j = 0; j < 8; j++) {
        int S = (j * 4 + w) * 64 + lane;
        int r = S >> 4, c = (S & 15) ^ (r & 15);
        gl_lds16(kb + (size_t)r * 128 + (c << 3), Klds + (j * 4 + w) * 1024);
      }
      __builtin_amdgcn_sched_barrier(0);
      const float* ab = adjg + (size_t)(it + 1) * 128;
#pragma unroll
      for (int et = 0; et < 2; et++) {
        const int e = we * 32 + et * 16 + l15;
#pragma unroll
        for (int lt = 0; lt < 4; lt++)
          av[et][lt] = *(const float4*)(ab + (size_t)e * 2048 + wh * 64 + lt * 16 + q * 4);
      }
      __builtin_amdgcn_sched_barrier(0);
    }

    // GEMM2: O[e][d-half] += P[e][l] * Vt[d][l], k = all 128 l
#pragma unroll
    for (int ks = 0; ks < 4; ks++) {
      s16x8 af[2], vf[4];
#pragma unroll
      for (int et = 0; et < 2; et++) {
        const int e = we * 32 + et * 16 + l15;
        af[et] = *(const s16x8*)(PL + e * 256 + (((ks * 4 + q) ^ l15) << 4));
      }
#pragma unroll
      for (int dt = 0; dt < 4; dt++) {
        int d = wh * 64 + dt * 16 + l15;
        vf[dt] = *(const s16x8*)(Vlds + d * 256 + (((ks * 4 + q) ^ l15) << 4));
      }
#pragma unroll
      for (int et = 0; et < 2; et++)
#pragma unroll
        for (int dt = 0; dt < 4; dt++)
          oacc[et][dt] = __builtin_amdgcn_mfma_f32_16x16x32_bf16(af[et], vf[dt], oacc[et][dt], 0, 0, 0);
    }

    BAR_C;  // Vlds reads done everywhere; K(it+1)/adj(it+1) remain in flight

    if (it < 15) {  // issue V(it+1) DMA; waited at [B](it+1) after GEMM1+softmax cover
      const unsigned short* vb = Vtg + (size_t)(it + 1) * 128;
#pragma unroll
      for (int j = 0; j < 8; j++) {
        int S = (j * 4 + w) * 64 + lane;
        int r = S >> 4, c = (S & 15) ^ (r & 15);
        gl_lds16(vb + (size_t)r * 2048 + (c << 3), Vlds + (j * 4 + w) * 1024);
      }
      __builtin_amdgcn_sched_barrier(0);
    }
  }

  // ---- epilogue ----
  // sden overlays the now-dead PL region (LDS total stays 81920 -> 2 blocks/CU)
  float* sden = (float*)(smem + 65536);
  if (tid < 64) sden[tid] = 0.0f;
  __syncthreads();  // sden zeroed (also: all PL reads done before overlay write)
  atomicAdd(&sden[we * 32 + l15], dp0);        // 8 contributors per e (2 wh x 4 q)
  atomicAdd(&sden[we * 32 + 16 + l15], dp1);

  // O2 [e=64][d=128] fp32 stride 132 overlays dead K/V tiles (33.8 KB)
  float* O2 = (float*)smem;
#pragma unroll
  for (int et = 0; et < 2; et++)
#pragma unroll
    for (int dt = 0; dt < 4; dt++) {
      const int eb = we * 32 + et * 16 + q * 4;
      const int d = wh * 64 + dt * 16 + l15;
      f32x4 v = oacc[et][dt];
#pragma unroll
      for (int r = 0; r < 4; r++) O2[(eb + r) * 132 + d] = v[r];
    }
  __syncthreads();  // O2 + sden visible

  // hp = gate * (O/den); LayerNorm; store. 4 threads per token, 32 features each.
  {
    const int e = tid >> 2, j = tid & 3;
    const float inv = 1.0f / sden[e];
    const float* row = O2 + e * 132 + j * 32;
    const float* gr = gateg + (size_t)e * 128 + j * 32;
    float4 x[8];
    float s1 = 0.f, s2 = 0.f;
#pragma unroll
    for (int i = 0; i < 8; i++) {
      float4 v = *(const float4*)(row + i * 4);
      float4 g = *(const float4*)(gr + i * 4);
      float4 hp;
      hp.x = v.x * inv * g.x; hp.y = v.y * inv * g.y;
      hp.z = v.z * inv * g.z; hp.w = v.w * inv * g.w;
      x[i] = hp;
      s1 += (hp.x + hp.y) + (hp.z + hp.w);
      s2 += (hp.x * hp.x + hp.y * hp.y) + (hp.z * hp.z + hp.w * hp.w);
    }
    s1 += __shfl_xor(s1, 1); s2 += __shfl_xor(s2, 1);
    s1 += __shfl_xor(s1, 2); s2 += __shfl_xor(s2, 2);
    const float mu = s1 * 0.0078125f;
    const float var = s2 * 0.0078125f - mu * mu;
    const float rs = rsqrtf(var + 1e-5f);
    float* orow = out + ((size_t)b * 2048 + e0 + e) * 128 + j * 32;
    const float* gg = ln_g + j * 32;
    const float* bb = ln_b + j * 32;
#pragma unroll
    for (int i = 0; i < 8; i++) {
      float4 gv = *(const float4*)(gg + i * 4);
      float4 bv = *(const float4*)(bb + i * 4);
      float4 o;
      o.x = (x[i].x - mu) * rs * gv.x + bv.x;
      o.y = (x[i].y - mu) * rs * gv.y + bv.y;
      o.z = (x[i].z - mu) * rs * gv.z + bv.z;
      o.w = (x[i].w - mu) * rs * gv.w + bv.w;
      *(float4*)(orow + i * 4) = o;
    }
  }
}

extern "C" void kernel_launch(void* const* d_in, const int* in_sizes, int n_in,
                              void* d_out, int out_size, void* d_ws, size_t ws_size,
                              hipStream_t stream) {
  const float* h = (const float*)d_in[0];
  const float* adj = (const float*)d_in[1];
  const float* op_emb = (const float*)d_in[2];
  const float* Wk = (const float*)d_in[3];
  const float* Wq = (const float*)d_in[4];
  const float* Wv = (const float*)d_in[5];
  const float* a_w = (const float*)d_in[6];
  const float* op_W = (const float*)d_in[7];
  const float* op_b = (const float*)d_in[8];
  const float* ln_g = (const float*)d_in[9];
  const float* ln_b = (const float*)d_in[10];
  char* ws = (char*)d_ws;
  float* out = (float*)d_out;

  k0_wt<<<dim3(4, 16), 256, 0, stream>>>(Wq, Wk, Wv, a_w, op_W, ws);
  k1_proj<<<dim3(4, 256), 256, 0, stream>>>(h, op_emb, op_b, ws);
  k2_attn<<<512, 256, 0, stream>>>(adj, ln_g, ln_b, ws, out);
}